// Round 10
// baseline (604.858 us; speedup 1.0000x reference)
//
#include <hip/hip_runtime.h>
#include <hip/hip_bf16.h>
#include <math.h>

#define NNODES 20000
#define NEDGES 640000
#define BSZ 256
#define GDIM 256
#define HID 512
#define INNER 2048
#define RANK 512
#define NCLS 3
#define NGENES 6640

typedef __attribute__((ext_vector_type(8))) short bf16x8;
typedef __attribute__((ext_vector_type(4))) float f32x4;
typedef __attribute__((ext_vector_type(4))) unsigned u32x4;   // native vectors: legal asm "v" operands
typedef __attribute__((ext_vector_type(2))) unsigned u32x2;

__device__ inline float bf2f(unsigned short u) {
    return __uint_as_float(((unsigned)u) << 16);
}
__device__ inline unsigned short f2bf(float f) {
    unsigned u = __float_as_uint(f);
    u = u + 0x7fff + ((u >> 16) & 1);   // RNE
    return (unsigned short)(u >> 16);
}
__device__ inline unsigned pk2(float a, float b) {
    return (unsigned)f2bf(a) | ((unsigned)f2bf(b) << 16);
}

// ---- device-coherent (cross-XCD) loads/stores: bypass L1/L2, complete at the
// memory-side coherence point. Used for cross-phase data inside persistent
// kernels so barriers need NO cache maintenance (weights stay L2-hot).
// Proven ladder: 565 -> 365 -> 199 -> 178 -> 112 -> 88 us (head_k).
__device__ inline u32x4 ld16_cg(const void* p) {
    u32x4 r;
    asm volatile("global_load_dwordx4 %0, %1, off sc0 sc1" : "=v"(r) : "v"(p) : "memory");
    return r;
}
__device__ inline u32x2 ld8_cg(const void* p) {
    u32x2 r;
    asm volatile("global_load_dwordx2 %0, %1, off sc0 sc1" : "=v"(r) : "v"(p) : "memory");
    return r;
}
__device__ inline int ld4i_cg(const int* p) {
    int r;
    asm volatile("global_load_dword %0, %1, off sc0 sc1" : "=v"(r) : "v"(p) : "memory");
    return r;
}
__device__ inline void st4f_cg(void* p, float v) {
    asm volatile("global_store_dword %0, %1, off sc0 sc1" :: "v"(p), "v"(v) : "memory");
}
__device__ inline void st4i_cg(int* p, int v) {
    asm volatile("global_store_dword %0, %1, off sc0 sc1" :: "v"(p), "v"(v) : "memory");
}
__device__ inline void st8_cg(void* p, u32x2 v) {
    asm volatile("global_store_dwordx2 %0, %1, off sc0 sc1" :: "v"(p), "v"(v) : "memory");
}
__device__ inline void st2_cg(void* p, unsigned short v) {
    unsigned w = v;
    asm volatile("global_store_short %0, %1, off sc0 sc1" :: "v"(p), "v"(w) : "memory");
}
__device__ inline void waitvm0(void) {
    asm volatile("s_waitcnt vmcnt(0)" ::: "memory");
    __builtin_amdgcn_sched_barrier(0);
}

// relaxed barrier: no wbl2/inv anywhere (cross-phase data goes through sc0sc1)
__device__ inline void gsync_arrive(int* bar) {
    waitvm0();
    __syncthreads();
    if (threadIdx.x == 0)
        __hip_atomic_fetch_add(bar, 1, __ATOMIC_RELAXED, __HIP_MEMORY_SCOPE_AGENT);
}
__device__ inline void gsync_wait(int* bar, int target) {
    if (threadIdx.x == 0) {
        while (__hip_atomic_load(bar, __ATOMIC_RELAXED, __HIP_MEMORY_SCOPE_AGENT) < target)
            __builtin_amdgcn_s_sleep(2);
    }
    // raw s_barrier: no vmcnt(0) drain -> prefetch loads stay in flight across it
    __builtin_amdgcn_s_barrier();
}
__device__ inline void gsync_c(int* bar, int target) {
    gsync_arrive(bar);
    gsync_wait(bar, target);
}

// ================= fused preprocessing: zero+LN1 | hist | scan x3 | scatter | flag | convert ====
// 256 blocks co-resident; 6 relaxed global barriers; all cross-phase ints via sc0sc1.
__global__ __launch_bounds__(256) void csr_k(
    const int* __restrict__ edge_src, const int* __restrict__ edge_dst,
    const float* __restrict__ edge_w, const int* __restrict__ node_indices,
    const float* __restrict__ partial_emb, const float* __restrict__ gnn_ln_s,
    const float* __restrict__ gnn_ln_b, unsigned short* __restrict__ ln_bf,
    int* __restrict__ counts, int* __restrict__ incl, int* __restrict__ bsums,
    int* __restrict__ boffs, int* __restrict__ row_start, int* __restrict__ cursor,
    int* __restrict__ flag, int2* __restrict__ ep, const float* __restrict__ gnn_w,
    const float* __restrict__ post_w, const float* __restrict__ pin_w,
    const float* __restrict__ blk_w1, const float* __restrict__ blk_w2,
    const float* __restrict__ pout_w, const float* __restrict__ gene,
    unsigned short* __restrict__ gnnT, unsigned short* __restrict__ postT,
    unsigned short* __restrict__ pinT, unsigned short* __restrict__ w1T,
    unsigned short* __restrict__ w2T, unsigned short* __restrict__ poutT,
    unsigned short* __restrict__ geneb, int* __restrict__ gbar) {
    __shared__ int s[256];
    __shared__ float sc[32][33];
    const int b = blockIdx.x, tid = threadIdx.x;
    const int gs = b * 256 + tid;
    const int NB_ = (NNODES + 255) / 256;

    // ph0a: zero counts & flag (cg: visible at IC to ph1 atomics)
    for (int i = gs; i < NNODES; i += 65536) {
        st4i_cg(counts + i, 0);
        st4i_cg(flag + i, 0);
    }
    // ph0b: GNN LayerNorm #1 (independent of CSR; plain stores, consumed next dispatch)
    {
        int lane = tid & 63;
        float4 s4 = ((const float4*)gnn_ln_s)[lane];
        float4 b4 = ((const float4*)gnn_ln_b)[lane];
        for (int row = b * 4 + (tid >> 6); row < NNODES; row += 1024) {
            float4 v = ((const float4*)(partial_emb + (size_t)row * GDIM))[lane];
            float sum = v.x + v.y + v.z + v.w;
#pragma unroll
            for (int off = 32; off >= 1; off >>= 1) sum += __shfl_xor(sum, off);
            float mu = sum / GDIM;
            float a = v.x - mu, b2 = v.y - mu, c = v.z - mu, d = v.w - mu;
            float sq = a * a + b2 * b2 + c * c + d * d;
#pragma unroll
            for (int off = 32; off >= 1; off >>= 1) sq += __shfl_xor(sq, off);
            float rstd = rsqrtf(sq / GDIM + 1e-5f);
            *(ushort4*)(ln_bf + (size_t)row * GDIM + lane * 4) =
                make_ushort4(f2bf(a * rstd * s4.x + b4.x), f2bf(b2 * rstd * s4.y + b4.y),
                             f2bf(c * rstd * s4.z + b4.z), f2bf(d * rstd * s4.w + b4.w));
        }
    }
    gsync_c(gbar, 256);
    // ph1: histogram (agent-scope atomics execute at IC; see zeroed counts)
    for (int e = gs; e < NEDGES; e += 65536) atomicAdd(&counts[edge_dst[e]], 1);
    gsync_c(gbar, 512);
    // ph2: per-256-chunk inclusive scans
    if (b < NB_) {
        int i = b * 256 + tid;
        int v = 0;
        if (i < NNODES) v = ld4i_cg(counts + i);
        waitvm0();
        s[tid] = v;
        __syncthreads();
        for (int off = 1; off < 256; off <<= 1) {
            int t2 = (tid >= off) ? s[tid - off] : 0;
            __syncthreads();
            s[tid] += t2;
            __syncthreads();
        }
        if (i < NNODES) st4i_cg(incl + i, s[tid]);
        if (tid == 255) st4i_cg(bsums + b, s[255]);
    }
    gsync_c(gbar, 768);
    // ph3: block 0 scans the chunk sums (exclusive -> boffs)
    if (b == 0) {
        int v = 0;
        if (tid < NB_) v = ld4i_cg(bsums + tid);
        waitvm0();
        s[tid] = v;
        __syncthreads();
        for (int off = 1; off < 256; off <<= 1) {
            int t2 = (tid >= off) ? s[tid - off] : 0;
            __syncthreads();
            s[tid] += t2;
            __syncthreads();
        }
        if (tid < NB_) st4i_cg(boffs + tid, s[tid] - v);
    }
    gsync_c(gbar, 1024);
    // ph4: row_start / cursor
    for (int i = gs; i < NNODES; i += 65536) {
        int a = ld4i_cg(incl + i);
        int c = ld4i_cg(counts + i);
        int o = ld4i_cg(boffs + (i >> 8));
        waitvm0();
        int st = a - c + o;
        st4i_cg(row_start + i, st);
        st4i_cg(cursor + i, st);
    }
    gsync_c(gbar, 1280);
    // ph5: scatter edges into CSR slots
    for (int e = gs; e < NEDGES; e += 65536) {
        int d = edge_dst[e];
        int p = atomicAdd(&cursor[d], 1);
        u32x2 pk;
        pk[0] = (unsigned)edge_src[e];
        pk[1] = __float_as_uint(edge_w[e]);
        st8_cg(ep + p, pk);
    }
    gsync_c(gbar, 1536);
    // ph6: flag rows needed by layers 2/3 (sel nodes + in-neighbors); block b = sel row b
    {
        int id = node_indices[b];
        int row = id < 0 ? 0 : id;
        if (tid == 0) st4i_cg(flag + row, 1);
        int beg = ld4i_cg(row_start + row);
        int cnt = ld4i_cg(counts + row);
        waitvm0();
        for (int t2 = tid; t2 < cnt; t2 += 256) {
            u32x2 e2 = ld8_cg(ep + beg + t2);
            waitvm0();
            st4i_cg(flag + (int)e2[0], 1);
        }
    }
    // ph7: weight conversions, grid-stride over 15100 tiles (no barrier needed:
    // consumers are later dispatches; kernel-end flush covers the stores)
    for (int tb = b; tb < 15100; tb += 256) {
        if (tb >= 13440) {   // gene fp32 -> bf16
            int t2 = tb - 13440;
            const float4* xp = (const float4*)gene;
            int i = t2 * 512 + tid * 2;
            float4 a = xp[i], c = xp[i + 1];
            *(ushort4*)(geneb + (size_t)i * 4) =
                make_ushort4(f2bf(a.x), f2bf(a.y), f2bf(a.z), f2bf(a.w));
            *(ushort4*)(geneb + (size_t)i * 4 + 4) =
                make_ushort4(f2bf(c.x), f2bf(c.y), f2bf(c.z), f2bf(c.w));
            continue;
        }
        const float* W;
        unsigned short* WT;
        int K, N, tile;
        if (tb < 192) {
            int l = tb >> 6;
            tile = tb & 63;
            W = gnn_w + (size_t)l * GDIM * GDIM;
            WT = gnnT + (size_t)l * GDIM * GDIM;
            K = GDIM; N = GDIM;
        } else if (tb < 256) {
            tile = tb - 192; W = post_w; WT = postT; K = GDIM; N = GDIM;
        } else if (tb < 384) {
            tile = tb - 256; W = pin_w; WT = pinT; K = GDIM; N = HID;
        } else if (tb < 6528) {
            int t2 = tb - 384;
            int l = t2 >> 10;
            tile = t2 & 1023;
            W = blk_w1 + (size_t)l * HID * INNER;
            WT = w1T + (size_t)l * INNER * HID;
            K = HID; N = INNER;
        } else if (tb < 12672) {
            int t2 = tb - 6528;
            int l = t2 >> 10;
            tile = t2 & 1023;
            W = blk_w2 + (size_t)l * INNER * HID;
            WT = w2T + (size_t)l * HID * INNER;
            K = INNER; N = HID;
        } else {
            tile = tb - 12672; W = pout_w; WT = poutT; K = HID; N = NCLS * RANK;
        }
        int ntx = N >> 5;
        int k0 = (tile / ntx) << 5;
        int n0 = (tile % ntx) << 5;
        int tx = tid & 31, ty = tid >> 5;
#pragma unroll
        for (int i = 0; i < 4; i++)
            sc[ty + 8 * i][tx] = W[(size_t)(k0 + ty + 8 * i) * N + n0 + tx];
        __syncthreads();
#pragma unroll
        for (int i = 0; i < 4; i++)
            WT[(size_t)(n0 + ty + 8 * i) * K + k0 + tx] = f2bf(sc[tx][ty + 8 * i]);
        __syncthreads();   // protect sc before next loop iteration
    }
}

// ---------------- GNN LayerNorm (D=256), bf16 out; optional row-flag skip ----------------
template <bool FLAGGED>
__global__ void lnb_k(const float* __restrict__ X, const float* __restrict__ sc,
                      const float* __restrict__ bi, unsigned short* __restrict__ Y, int M,
                      const int* __restrict__ flag) {
    int row = blockIdx.x * 4 + (threadIdx.x >> 6);
    int lane = threadIdx.x & 63;
    if (row >= M) return;
    if (FLAGGED && !flag[row]) return;   // wave-uniform skip: stale rows never consumed
    float4 v = ((const float4*)(X + (size_t)row * GDIM))[lane];
    float sum = v.x + v.y + v.z + v.w;
#pragma unroll
    for (int off = 32; off >= 1; off >>= 1) sum += __shfl_xor(sum, off);
    float mu = sum / GDIM;
    float a = v.x - mu, b = v.y - mu, c = v.z - mu, d = v.w - mu;
    float sq = a * a + b * b + c * c + d * d;
#pragma unroll
    for (int off = 32; off >= 1; off >>= 1) sq += __shfl_xor(sq, off);
    float rstd = rsqrtf(sq / GDIM + 1e-5f);
    float4 s4 = ((const float4*)sc)[lane];
    float4 b4 = ((const float4*)bi)[lane];
    *(ushort4*)(Y + (size_t)row * GDIM + lane * 4) =
        make_ushort4(f2bf(a * rstd * s4.x + b4.x), f2bf(b * rstd * s4.y + b4.y),
                     f2bf(c * rstd * s4.z + b4.z), f2bf(d * rstd * s4.w + b4.w));
}

// ---------------- CSR aggregation, 16-deep MLP unroll ----------------
__device__ inline void agg_row(int beg, int cnt, int lane, const int2* __restrict__ ep,
                               const unsigned short* __restrict__ H, float& a0, float& a1,
                               float& a2, float& a3) {
    int t = 0;
    for (; t + 16 <= cnt; t += 16) {
        int2 e[16];
#pragma unroll
        for (int u = 0; u < 16; u++) e[u] = ep[beg + t + u];
        ushort4 v[16];
#pragma unroll
        for (int u = 0; u < 16; u++)
            v[u] = *(const ushort4*)(H + (size_t)e[u].x * GDIM + lane * 4);
#pragma unroll
        for (int u = 0; u < 16; u++) {
            float w = __int_as_float(e[u].y);
            a0 = fmaf(bf2f(v[u].x), w, a0);
            a1 = fmaf(bf2f(v[u].y), w, a1);
            a2 = fmaf(bf2f(v[u].z), w, a2);
            a3 = fmaf(bf2f(v[u].w), w, a3);
        }
    }
    for (; t + 4 <= cnt; t += 4) {
        int2 e[4];
#pragma unroll
        for (int u = 0; u < 4; u++) e[u] = ep[beg + t + u];
        ushort4 v[4];
#pragma unroll
        for (int u = 0; u < 4; u++)
            v[u] = *(const ushort4*)(H + (size_t)e[u].x * GDIM + lane * 4);
#pragma unroll
        for (int u = 0; u < 4; u++) {
            float w = __int_as_float(e[u].y);
            a0 = fmaf(bf2f(v[u].x), w, a0);
            a1 = fmaf(bf2f(v[u].y), w, a1);
            a2 = fmaf(bf2f(v[u].z), w, a2);
            a3 = fmaf(bf2f(v[u].w), w, a3);
        }
    }
    for (; t < cnt; t++) {
        int2 e = ep[beg + t];
        float w = __int_as_float(e.y);
        ushort4 v = *(const ushort4*)(H + (size_t)e.x * GDIM + lane * 4);
        a0 = fmaf(bf2f(v.x), w, a0);
        a1 = fmaf(bf2f(v.y), w, a1);
        a2 = fmaf(bf2f(v.z), w, a2);
        a3 = fmaf(bf2f(v.w), w, a3);
    }
}

template <bool FLAGGED>
__global__ void aggb_k(const int* __restrict__ row_start, const int* __restrict__ counts,
                       const int2* __restrict__ ep, const unsigned short* __restrict__ H,
                       unsigned short* __restrict__ AGG, int n, const int* __restrict__ flag) {
    int row = blockIdx.x * 4 + (threadIdx.x >> 6);
    int lane = threadIdx.x & 63;
    if (row >= n) return;
    if (FLAGGED && !flag[row]) return;   // skip rows whose x2 is never consumed
    float a0 = 0.f, a1 = 0.f, a2 = 0.f, a3 = 0.f;
    agg_row(row_start[row], counts[row], lane, ep, H, a0, a1, a2, a3);
    *(ushort4*)(AGG + (size_t)row * GDIM + lane * 4) =
        make_ushort4(f2bf(a0), f2bf(a1), f2bf(a2), f2bf(a3));
}

// ---------------- bf16 MFMA GEMM (full-K, fp32 out, fused epilogue) — GNN L1/L2 & logits ----------------
template <int ACT, bool RES, bool BIAS>
__global__ __launch_bounds__(256) void mgemm_k(const unsigned short* __restrict__ A,
                                               const unsigned short* __restrict__ BT,
                                               const float* __restrict__ bias,
                                               const float* __restrict__ R,
                                               float* __restrict__ C, int M, int N, int K) {
    __shared__ unsigned short As[128 * 32];
    __shared__ unsigned short Bs[128 * 32];
    int m0 = blockIdx.y * 128, n0 = blockIdx.x * 128;
    int tid = threadIdx.x;
    int wave = tid >> 6, lane = tid & 63;
    int wm = (wave >> 1) * 64, wn = (wave & 1) * 64;
    int lrow = lane & 15, lq = lane >> 4;

    f32x4 acc[4][4];
    const f32x4 zz = {0.f, 0.f, 0.f, 0.f};
#pragma unroll
    for (int i = 0; i < 4; i++)
#pragma unroll
        for (int j = 0; j < 4; j++) acc[i][j] = zz;

    int r0 = tid >> 2;
    int q = tid & 3;

    for (int k0 = 0; k0 < K; k0 += 32) {
#pragma unroll
        for (int p = 0; p < 2; p++) {
            int row = r0 + p * 64;
            int gm = m0 + row;
            uint4 va = make_uint4(0, 0, 0, 0);
            if (gm < M) va = *(const uint4*)(A + (size_t)gm * K + k0 + q * 8);
            *(uint4*)&As[row * 32 + q * 8] = va;
            int gn = n0 + row;
            uint4 vb = make_uint4(0, 0, 0, 0);
            if (gn < N) vb = *(const uint4*)(BT + (size_t)gn * K + k0 + q * 8);
            *(uint4*)&Bs[row * 32 + q * 8] = vb;
        }
        __syncthreads();
        bf16x8 af[4], bf[4];
#pragma unroll
        for (int i = 0; i < 4; i++)
            af[i] = *(const bf16x8*)&As[(wm + i * 16 + lrow) * 32 + lq * 8];
#pragma unroll
        for (int j = 0; j < 4; j++)
            bf[j] = *(const bf16x8*)&Bs[(wn + j * 16 + lrow) * 32 + lq * 8];
#pragma unroll
        for (int i = 0; i < 4; i++)
#pragma unroll
            for (int j = 0; j < 4; j++)
                acc[i][j] =
                    __builtin_amdgcn_mfma_f32_16x16x32_bf16(af[i], bf[j], acc[i][j], 0, 0, 0);
        __syncthreads();
    }

#pragma unroll
    for (int i = 0; i < 4; i++) {
#pragma unroll
        for (int j = 0; j < 4; j++) {
            int gn = n0 + wn + j * 16 + lrow;
            if (gn >= N) continue;
            float bv = BIAS ? bias[gn] : 0.f;
#pragma unroll
            for (int r = 0; r < 4; r++) {
                int gm = m0 + wm + i * 16 + lq * 4 + r;
                if (gm >= M) continue;
                float v = acc[i][j][r] + bv;
                if (ACT == 1) v = fmaxf(v, 0.f);
                if (RES) v += R[(size_t)gm * N + gn];
                C[(size_t)gm * N + gn] = v;
            }
        }
    }
}

// ================= fused persistent head (v7: + aggsel/L3/post prologue phases) ======
// Group g (blocks g*32..g*32+31) owns batch rows [32g,32g+32); per-group barriers
// (proven 178 -> 112); arrive->prefetch->wait split (proven 122 -> 88). NEW: the three
// 256-row tail ops (aggsel gather, GNN-L3 GEMM, post GEMM) are group-local -> folded
// in as 3 prologue phases, killing 3 dispatches (+gaps).

#define HGRID 256
#define LDPA 520   // ushort row stride for K<=512 tiles: 1040B -> bank-optimal b128 reads
#define GBLK 32    // blocks per group

// issue ROWSxKC bf16 tile loads (all outstanding), NL = ROWS*KC/2048 regs/thread
template <int ROWS, int KC, bool CG>
__device__ inline void stage_issue(const unsigned short* src, int ld, u32x4* regs) {
    constexpr int NL = ROWS * KC / 8 / 256;
    int tid = threadIdx.x;
#pragma unroll
    for (int it = 0; it < NL; it++) {
        int unit = it * 256 + tid;
        int row = unit / (KC / 8);
        int ucol = unit % (KC / 8);
        const unsigned short* p = src + (size_t)row * ld + ucol * 8;
        if (CG) regs[it] = ld16_cg(p);
        else regs[it] = *(const u32x4*)p;
    }
}
template <int ROWS, int KC>
__device__ inline void stage_write(unsigned short* dst, const u32x4* regs) {
    constexpr int NL = ROWS * KC / 8 / 256;
    int tid = threadIdx.x;
#pragma unroll
    for (int it = 0; it < NL; it++) {
        int unit = it * 256 + tid;
        int row = unit / (KC / 8);
        int ucol = unit % (KC / 8);
        *(u32x4*)&dst[row * LDPA + ucol * 8] = regs[it];
    }
}

// uninterrupted MFMA stream over the fully-staged tile (no inner barriers)
template <int KC>
__device__ inline void mma_all(const unsigned short* As, const unsigned short* Bs, f32x4 acc[2]) {
    int tid = threadIdx.x, wave = tid >> 6, lane = tid & 63;
    int wm = (wave >> 1) * 16, wn = (wave & 1) * 32;
    int lrow = lane & 15, lq = lane >> 4;
#pragma unroll
    for (int kk = 0; kk < KC / 32; kk++) {
        bf16x8 af = *(const bf16x8*)&As[(wm + lrow) * LDPA + kk * 32 + lq * 8];
#pragma unroll
        for (int j = 0; j < 2; j++) {
            bf16x8 bfr = *(const bf16x8*)&Bs[(wn + j * 16 + lrow) * LDPA + kk * 32 + lq * 8];
            acc[j] = __builtin_amdgcn_mfma_f32_16x16x32_bf16(af, bfr, acc[j], 0, 0, 0);
        }
    }
}

__global__ __launch_bounds__(256) void head_k(
    const int* __restrict__ node_indices, const int* __restrict__ row_start,
    const int* __restrict__ counts, const int2* __restrict__ ep,
    const unsigned short* __restrict__ lnbf, const unsigned short* __restrict__ gnnT3,
    const float* __restrict__ gnnb3, const float* __restrict__ xb,
    const unsigned short* __restrict__ postT, const float* __restrict__ post_b,
    const float* __restrict__ oov_emb, unsigned short* __restrict__ aggselb,
    unsigned short* __restrict__ pertinbf, unsigned short* __restrict__ pertbf,
    const unsigned short* __restrict__ pinT, const float* __restrict__ pin_b,
    const float* __restrict__ blk_ln_s, const float* __restrict__ blk_ln_b,
    const unsigned short* __restrict__ w1T, const float* __restrict__ blk_b1,
    const unsigned short* __restrict__ w2T, const float* __restrict__ blk_b2,
    const unsigned short* __restrict__ poutT, const float* __restrict__ pout_b,
    float* __restrict__ hbuf, unsigned short* __restrict__ z1bf,
    unsigned short* __restrict__ projb, int* __restrict__ bar) {
    __shared__ unsigned short As[32 * LDPA];   // 33.3 KB
    __shared__ unsigned short Bs[64 * LDPA];   // 66.6 KB
    int b = blockIdx.x;
    int g = b >> 5;          // row-group 0..7: batch rows [g*32, g*32+32)
    int t = b & 31;          // rank within group; b%8 == t%8 -> XCD locality by n-slice
    int* gbar = bar + g * 32;   // per-group counter, 128 B apart
    int m0 = g * 32;
    int tid = threadIdx.x;
    int wave = tid >> 6, lane = tid & 63;
    int wm = (wave >> 1) * 16, wn = (wave & 1) * 32;
    int lrow = lane & 15, lq = lane >> 4;
    int ph = 0;
    f32x4 acc[2];
    const f32x4 zz = {0.f, 0.f, 0.f, 0.f};
    u32x4 pf[16];   // weight prefetch registers, live across the barrier (1 block/CU)

    // ---- P-3: aggsel — block t gathers for batch row m0+t (4-wave edge split + LDS reduce)
    {
        int bb = m0 + t;
        int id = node_indices[bb];
        int row = id < 0 ? 0 : id;
        int beg = row_start[row], cnt = counts[row];
        float a0 = 0.f, a1 = 0.f, a2 = 0.f, a3 = 0.f;
        for (int e2 = wave; e2 < cnt; e2 += 4) {
            int2 ed = ep[beg + e2];
            float w = __int_as_float(ed.y);
            ushort4 v = *(const ushort4*)(lnbf + (size_t)ed.x * GDIM + lane * 4);
            a0 = fmaf(bf2f(v.x), w, a0);
            a1 = fmaf(bf2f(v.y), w, a1);
            a2 = fmaf(bf2f(v.z), w, a2);
            a3 = fmaf(bf2f(v.w), w, a3);
        }
        float* red = (float*)As;
        red[wave * 256 + lane * 4 + 0] = a0;
        red[wave * 256 + lane * 4 + 1] = a1;
        red[wave * 256 + lane * 4 + 2] = a2;
        red[wave * 256 + lane * 4 + 3] = a3;
        __syncthreads();
        if (wave == 0) {
            float s0 = red[lane * 4] + red[256 + lane * 4] + red[512 + lane * 4] +
                       red[768 + lane * 4];
            float s1 = red[lane * 4 + 1] + red[256 + lane * 4 + 1] + red[512 + lane * 4 + 1] +
                       red[768 + lane * 4 + 1];
            float s2 = red[lane * 4 + 2] + red[256 + lane * 4 + 2] + red[512 + lane * 4 + 2] +
                       red[768 + lane * 4 + 2];
            float s3 = red[lane * 4 + 3] + red[256 + lane * 4 + 3] + red[512 + lane * 4 + 3] +
                       red[768 + lane * 4 + 3];
            u32x2 pk;
            pk[0] = pk2(s0, s1);
            pk[1] = pk2(s2, s3);
            st8_cg(aggselb + (size_t)bb * GDIM + lane * 4, pk);
        }
    }
    gsync_c(gbar, ++ph * GBLK);

    // ---- P-2: pertin = relu(aggsel @ W3 + b3) + xb[idx]  (t<4: 32x64 col slices, K=256)
    if (t < 4) {
        int n0 = t * 64;
        u32x4 wreg[8], areg[4];
        stage_issue<64, 256, false>(gnnT3 + (size_t)n0 * GDIM, GDIM, wreg);
        stage_issue<32, 256, true>(aggselb + (size_t)m0 * GDIM, GDIM, areg);
        waitvm0();
        stage_write<64, 256>(Bs, wreg);
        stage_write<32, 256>(As, areg);
        __syncthreads();
        acc[0] = zz; acc[1] = zz;
        mma_all<256>(As, Bs, acc);
#pragma unroll
        for (int j = 0; j < 2; j++) {
            int gn = n0 + wn + j * 16 + lrow;
            float bv = gnnb3[gn];
#pragma unroll
            for (int r = 0; r < 4; r++) {
                int gmb = m0 + wm + lq * 4 + r;
                float v = fmaxf(acc[j][r] + bv, 0.f);
                int id = node_indices[gmb];
                int safe = id < 0 ? 0 : id;
                v += xb[(size_t)safe * GDIM + gn];
                st2_cg(pertinbf + (size_t)gmb * GDIM + gn, f2bf(v));
            }
        }
    }
    gsync_c(gbar, ++ph * GBLK);

    // ---- P-1: pert = pertin @ postW + post_b; OOV rows replaced by oov_emb
    if (t < 4) {
        int n0 = t * 64;
        u32x4 wreg[8], areg[4];
        stage_issue<64, 256, false>(postT + (size_t)n0 * GDIM, GDIM, wreg);
        stage_issue<32, 256, true>(pertinbf + (size_t)m0 * GDIM, GDIM, areg);
        waitvm0();
        stage_write<64, 256>(Bs, wreg);
        stage_write<32, 256>(As, areg);
        __syncthreads();
        acc[0] = zz; acc[1] = zz;
        mma_all<256>(As, Bs, acc);
#pragma unroll
        for (int j = 0; j < 2; j++) {
            int gn = n0 + wn + j * 16 + lrow;
            float bv = post_b[gn];
#pragma unroll
            for (int r = 0; r < 4; r++) {
                int gmb = m0 + wm + lq * 4 + r;
                float v = acc[j][r] + bv;
                if (node_indices[gmb] < 0) v = oov_emb[gn];
                st2_cg(pertbf + (size_t)gmb * GDIM + gn, f2bf(v));
            }
        }
    }
    gsync_c(gbar, ++ph * GBLK);

    // ---- P0: h[g-rows] = pert @ pinT + pin_b  (8 active blocks/group, full K=256)
    if (t < 8) {
        int n0 = t * 64;
        u32x4 wreg[8], areg[4];
        stage_issue<64, 256, false>(pinT + (size_t)n0 * GDIM, GDIM, wreg);
        stage_issue<32, 256, true>(pertbf + (size_t)m0 * GDIM, GDIM, areg);
        waitvm0();
        stage_write<64, 256>(Bs, wreg);
        stage_write<32, 256>(As, areg);
        __syncthreads();
        acc[0] = zz; acc[1] = zz;
        mma_all<256>(As, Bs, acc);
#pragma unroll
        for (int j = 0; j < 2; j++) {
            int gn = n0 + wn + j * 16 + lrow;
            float bv = pin_b[gn];
#pragma unroll
            for (int r = 0; r < 4; r++) {
                int gm = m0 + wm + lq * 4 + r;
                st4f_cg(hbuf + (size_t)gm * HID + gn, acc[j][r] + bv);
            }
        }
    }
    // arrive -> issue layer-0 w1 prefetch -> poll: load latency hides under the poll
    gsync_arrive(gbar);
    stage_issue<64, 512, false>(w1T + (size_t)t * 64 * HID, HID, pf);
    gsync_wait(gbar, ++ph * GBLK);

    for (int i = 0; i < 6; i++) {
        {   // A: z1[g-rows] = gelu(LN_i(h) @ w1 + b1); 32 blocks x 64-col slices, K=512
            int n0 = t * 64;
            u32x4 hreg[16];
#pragma unroll
            for (int rr = 0; rr < 8; rr++) {
                const float* p = hbuf + (size_t)(m0 + wave * 8 + rr) * HID + lane * 8;
                hreg[2 * rr] = ld16_cg(p);
                hreg[2 * rr + 1] = ld16_cg(p + 4);
            }
            stage_write<64, 512>(Bs, pf);   // compiler inserts counted wait for pf here
            waitvm0();
            // inline LayerNorm (redundant across the 32 n-slices, cheap) -> bf16 As
            const float* ls = blk_ln_s + (size_t)i * HID;
            const float* lb = blk_ln_b + (size_t)i * HID;
            float4 s0 = ((const float4*)ls)[lane * 2], s1 = ((const float4*)ls)[lane * 2 + 1];
            float4 t0 = ((const float4*)lb)[lane * 2], t1 = ((const float4*)lb)[lane * 2 + 1];
#pragma unroll
            for (int rr = 0; rr < 8; rr++) {
                float f0 = __uint_as_float(hreg[2 * rr][0]);
                float f1 = __uint_as_float(hreg[2 * rr][1]);
                float f2 = __uint_as_float(hreg[2 * rr][2]);
                float f3 = __uint_as_float(hreg[2 * rr][3]);
                float f4 = __uint_as_float(hreg[2 * rr + 1][0]);
                float f5 = __uint_as_float(hreg[2 * rr + 1][1]);
                float f6 = __uint_as_float(hreg[2 * rr + 1][2]);
                float f7 = __uint_as_float(hreg[2 * rr + 1][3]);
                float sum = f0 + f1 + f2 + f3 + f4 + f5 + f6 + f7;
#pragma unroll
                for (int off = 32; off >= 1; off >>= 1) sum += __shfl_xor(sum, off);
                float mu = sum * (1.f / HID);
                float d0 = f0 - mu, d1 = f1 - mu, d2 = f2 - mu, d3 = f3 - mu;
                float d4 = f4 - mu, d5 = f5 - mu, d6 = f6 - mu, d7 = f7 - mu;
                float sq = d0 * d0 + d1 * d1 + d2 * d2 + d3 * d3 + d4 * d4 + d5 * d5 +
                           d6 * d6 + d7 * d7;
#pragma unroll
                for (int off = 32; off >= 1; off >>= 1) sq += __shfl_xor(sq, off);
                float rstd = rsqrtf(sq * (1.f / HID) + 1e-5f);
                u32x4 pk;
                pk[0] = pk2(d0 * rstd * s0.x + t0.x, d1 * rstd * s0.y + t0.y);
                pk[1] = pk2(d2 * rstd * s0.z + t0.z, d3 * rstd * s0.w + t0.w);
                pk[2] = pk2(d4 * rstd * s1.x + t1.x, d5 * rstd * s1.y + t1.y);
                pk[3] = pk2(d6 * rstd * s1.z + t1.z, d7 * rstd * s1.w + t1.w);
                *(u32x4*)&As[(wave * 8 + rr) * LDPA + lane * 8] = pk;
            }
            __syncthreads();
            acc[0] = zz; acc[1] = zz;
            mma_all<512>(As, Bs, acc);
#pragma unroll
            for (int j = 0; j < 2; j++) {
                int gn = n0 + wn + j * 16 + lrow;
                float bv = blk_b1[(size_t)i * INNER + gn];
#pragma unroll
                for (int r = 0; r < 4; r++) {
                    int gm = m0 + wm + lq * 4 + r;
                    float v = acc[j][r] + bv;
                    v = 0.5f * v * (1.f + erff(v * 0.70710678118654752f));
                    st2_cg(z1bf + (size_t)gm * INNER + gn, f2bf(v));
                }
            }
        }
        // arrive -> prefetch my B-phase w2 slice -> poll
        gsync_arrive(gbar);
        stage_issue<64, 512, false>(
            w2T + (size_t)i * HID * INNER + (size_t)(t & 7) * 64 * INNER + (t >> 3) * 512,
            INNER, pf);
        gsync_wait(gbar, ++ph * GBLK);
        {   // B: h[g-rows] += z1 @ w2 K-chunk (+b2 once via s==0); 8n x 4s per group
            int s = t >> 3, n0 = (t & 7) * 64, kbeg = s * 512;
            u32x4 areg[8];
            stage_issue<32, 512, true>(z1bf + (size_t)m0 * INNER + kbeg, INNER, areg);
            stage_write<64, 512>(Bs, pf);
            waitvm0();
            stage_write<32, 512>(As, areg);
            __syncthreads();
            acc[0] = zz; acc[1] = zz;
            mma_all<512>(As, Bs, acc);
#pragma unroll
            for (int j = 0; j < 2; j++) {
                int gn = n0 + wn + j * 16 + lrow;
                float bv = (s == 0) ? blk_b2[(size_t)i * HID + gn] : 0.f;
#pragma unroll
                for (int r = 0; r < 4; r++) {
                    int gm = m0 + wm + lq * 4 + r;
                    __hip_atomic_fetch_add(hbuf + (size_t)gm * HID + gn, acc[j][r] + bv,
                                           __ATOMIC_RELAXED, __HIP_MEMORY_SCOPE_AGENT);
                }
            }
        }
        // arrive -> prefetch next A-phase w1 (or pout slice after last layer) -> poll
        gsync_arrive(gbar);
        if (i < 5)
            stage_issue<64, 512, false>(
                w1T + (size_t)(i + 1) * INNER * HID + (size_t)t * 64 * HID, HID, pf);
        else if (t < 24)
            stage_issue<64, 512, false>(poutT + (size_t)t * 64 * HID, HID, pf);
        gsync_wait(gbar, ++ph * GBLK);
    }

    // ---- pout: projb[g-rows] = h @ poutT + pout_b  (24 active blocks/group, K=512)
    if (t < 24) {
        int n0 = t * 64;
        u32x4 areg[16];
#pragma unroll
        for (int it = 0; it < 16; it++) {
            int unit = it * 256 + tid;
            int row = unit >> 7, ucol = unit & 127;   // 128 units of 4 f32 per row
            areg[it] = ld16_cg(hbuf + (size_t)(m0 + row) * HID + ucol * 4);
        }
        stage_write<64, 512>(Bs, pf);
        waitvm0();
#pragma unroll
        for (int it = 0; it < 16; it++) {
            int unit = it * 256 + tid;
            int row = unit >> 7, ucol = unit & 127;
            float a = __uint_as_float(areg[it][0]), c = __uint_as_float(areg[it][1]);
            float d = __uint_as_float(areg[it][2]), e = __uint_as_float(areg[it][3]);
            uint2 w2v;
            w2v.x = pk2(a, c);
            w2v.y = pk2(d, e);
            *(uint2*)&As[row * LDPA + ucol * 4] = w2v;
        }
        __syncthreads();
        acc[0] = zz; acc[1] = zz;
        mma_all<512>(As, Bs, acc);
#pragma unroll
        for (int j = 0; j < 2; j++) {
            int gn = n0 + wn + j * 16 + lrow;
            float bv = pout_b[gn];
#pragma unroll
            for (int r = 0; r < 4; r++) {
                int gm = m0 + wm + lq * 4 + r;
                projb[(size_t)gm * (NCLS * RANK) + gn] = f2bf(acc[j][r] + bv);
            }
        }
    }
}

// ---------------- launch ----------------
extern "C" void kernel_launch(void* const* d_in, const int* in_sizes, int n_in,
                              void* d_out, int out_size, void* d_ws, size_t ws_size,
                              hipStream_t stream) {
    const int* node_indices = (const int*)d_in[0];
    const int* edge_src = (const int*)d_in[1];
    const int* edge_dst = edge_src + NEDGES;
    const float* edge_w = (const float*)d_in[2];
    const float* partial_emb = (const float*)d_in[3];
    const float* oov_emb = (const float*)d_in[4];
    const float* gnn_ln_s = (const float*)d_in[5];
    const float* gnn_ln_b = (const float*)d_in[6];
    const float* gnn_w = (const float*)d_in[7];
    const float* gnn_b = (const float*)d_in[8];
    const float* post_w = (const float*)d_in[9];
    const float* post_b = (const float*)d_in[10];
    const float* pin_w = (const float*)d_in[11];
    const float* pin_b = (const float*)d_in[12];
    const float* blk_ln_s = (const float*)d_in[13];
    const float* blk_ln_b = (const float*)d_in[14];
    const float* blk_w1 = (const float*)d_in[15];
    const float* blk_b1 = (const float*)d_in[16];
    const float* blk_w2 = (const float*)d_in[17];
    const float* blk_b2 = (const float*)d_in[18];
    const float* pout_w = (const float*)d_in[19];
    const float* pout_b = (const float*)d_in[20];
    const float* gene = (const float*)d_in[21];
    float* out = (float*)d_out;

    char* p = (char*)d_ws;
    auto alloc = [&](size_t bytes) {
        char* r = p;
        p += (bytes + 255) & ~(size_t)255;
        return r;
    };
    int* counts = (int*)alloc(NNODES * 4);
    int* incl = (int*)alloc(NNODES * 4);
    int* bsums = (int*)alloc(128 * 4);
    int* boffs = (int*)alloc(128 * 4);
    int* row_start = (int*)alloc(NNODES * 4);
    int* cursor = (int*)alloc(NNODES * 4);
    int* flag = (int*)alloc(NNODES * 4);
    int2* epack = (int2*)alloc((size_t)NEDGES * 8);
    // 'part': GNN phase scratch = ln_bf + aggbf (bf16)
    float* part = (float*)alloc((size_t)NNODES * GDIM * 4);
    unsigned short* ln_bf = (unsigned short*)part;
    unsigned short* aggbf = (unsigned short*)((char*)part + (size_t)NNODES * GDIM * 2);
    float* xa = (float*)alloc((size_t)NNODES * GDIM * 4);
    float* xb = (float*)alloc((size_t)NNODES * GDIM * 4);
    float* hbuf = (float*)alloc((size_t)BSZ * HID * 4);
    unsigned short* aggselb = (unsigned short*)alloc((size_t)BSZ * GDIM * 2);
    unsigned short* pertinbf = (unsigned short*)alloc((size_t)BSZ * GDIM * 2);
    unsigned short* pertbf = (unsigned short*)alloc((size_t)BSZ * GDIM * 2);
    unsigned short* z1bf = (unsigned short*)alloc((size_t)BSZ * INNER * 2);
    unsigned short* projb = (unsigned short*)alloc((size_t)BSZ * NCLS * RANK * 2);
    unsigned short* gnnT = (unsigned short*)alloc((size_t)3 * GDIM * GDIM * 2);
    unsigned short* postT = (unsigned short*)alloc((size_t)GDIM * GDIM * 2);
    unsigned short* pinT = (unsigned short*)alloc((size_t)HID * GDIM * 2);
    unsigned short* w1T = (unsigned short*)alloc((size_t)6 * INNER * HID * 2);
    unsigned short* w2T = (unsigned short*)alloc((size_t)6 * HID * INNER * 2);
    unsigned short* poutT = (unsigned short*)alloc((size_t)NCLS * RANK * HID * 2);
    unsigned short* geneb = (unsigned short*)alloc((size_t)NGENES * RANK * 2);
    int* bar = (int*)alloc(2048);   // 8 head group counters (128B apart) + csr counter @ +1024B

    // one memset: all barrier counters
    (void)hipMemsetAsync(bar, 0, 2048, stream);

    // fused preprocessing: zeroing + LN#1 + CSR build + flag + ALL weight conversions
    csr_k<<<256, 256, 0, stream>>>(edge_src, edge_dst, edge_w, node_indices, partial_emb,
                                   gnn_ln_s, gnn_ln_b, ln_bf, counts, incl, bsums, boffs,
                                   row_start, cursor, flag, epack, gnn_w, post_w, pin_w, blk_w1,
                                   blk_w2, pout_w, gene, gnnT, postT, pinT, w1T, w2T, poutT,
                                   geneb, bar + 256);

    // GNN layer 1 (full): LN#1 already done in csr_k
    aggb_k<false><<<(NNODES + 3) / 4, 256, 0, stream>>>(row_start, counts, epack, ln_bf, aggbf,
                                                        NNODES, nullptr);
    mgemm_k<1, true, true><<<dim3(GDIM / 128, (NNODES + 127) / 128), 256, 0, stream>>>(
        aggbf, gnnT, gnn_b, partial_emb, xa, NNODES, GDIM, GDIM);
    // GNN layer 2 (flagged rows only)
    lnb_k<false><<<(NNODES + 3) / 4, 256, 0, stream>>>(xa, gnn_ln_s + GDIM, gnn_ln_b + GDIM,
                                                       ln_bf, NNODES, nullptr);
    aggb_k<true><<<(NNODES + 3) / 4, 256, 0, stream>>>(row_start, counts, epack, ln_bf, aggbf,
                                                       NNODES, flag);
    mgemm_k<1, true, true><<<dim3(GDIM / 128, (NNODES + 127) / 128), 256, 0, stream>>>(
        aggbf, gnnT + (size_t)GDIM * GDIM, gnn_b + GDIM, xa, xb, NNODES, GDIM, GDIM);
    // layer 3 LN: only flagged rows (sources of selected rows' edges)
    lnb_k<true><<<(NNODES + 3) / 4, 256, 0, stream>>>(xb, gnn_ln_s + 2 * GDIM,
                                                      gnn_ln_b + 2 * GDIM, ln_bf, NNODES, flag);

    // fused head: aggsel + L3 + post + pin + 6 blocks + pout (16 group barriers)
    head_k<<<HGRID, 256, 0, stream>>>(node_indices, row_start, counts, epack, ln_bf,
                                      gnnT + (size_t)2 * GDIM * GDIM, gnn_b + 2 * GDIM, xb,
                                      postT, post_b, oov_emb, aggselb, pertinbf, pertbf, pinT,
                                      pin_b, blk_ln_s, blk_ln_b, w1T, blk_b1, w2T, blk_b2,
                                      poutT, pout_b, hbuf, z1bf, projb, bar);

    // logits
    mgemm_k<0, false, false><<<dim3((NGENES + 127) / 128, (BSZ * NCLS) / 128), 256, 0, stream>>>(
        projb, geneb, nullptr, nullptr, out, BSZ * NCLS, NGENES, RANK);
}

// Round 11
// 510.828 us; speedup vs baseline: 1.1841x; 1.1841x over previous
//
#include <hip/hip_runtime.h>
#include <hip/hip_bf16.h>
#include <math.h>

#define NNODES 20000
#define NEDGES 640000
#define BSZ 256
#define GDIM 256
#define HID 512
#define INNER 2048
#define RANK 512
#define NCLS 3
#define NGENES 6640

typedef __attribute__((ext_vector_type(8))) short bf16x8;
typedef __attribute__((ext_vector_type(4))) float f32x4;
typedef __attribute__((ext_vector_type(4))) unsigned u32x4;   // native vectors: legal asm "v" operands
typedef __attribute__((ext_vector_type(2))) unsigned u32x2;

__device__ inline float bf2f(unsigned short u) {
    return __uint_as_float(((unsigned)u) << 16);
}
__device__ inline unsigned short f2bf(float f) {
    unsigned u = __float_as_uint(f);
    u = u + 0x7fff + ((u >> 16) & 1);   // RNE
    return (unsigned short)(u >> 16);
}
__device__ inline unsigned pk2(float a, float b) {
    return (unsigned)f2bf(a) | ((unsigned)f2bf(b) << 16);
}

// ---- device-coherent (cross-XCD) loads/stores: bypass L1/L2, complete at the
// memory-side coherence point. Used ONLY for cross-phase data inside the
// persistent head so its barriers need NO cache maintenance (weights stay
// L2-hot). Proven head ladder: 565 -> 365 -> 199 -> 178 -> 112 -> 88 us.
// Round-10 lesson: do NOT use this for bulk streaming writes (ln_bf, weight
// converts) — doubles WRITE_SIZE and starves TLP in a 256-block grid.
__device__ inline u32x4 ld16_cg(const void* p) {
    u32x4 r;
    asm volatile("global_load_dwordx4 %0, %1, off sc0 sc1" : "=v"(r) : "v"(p) : "memory");
    return r;
}
__device__ inline u32x2 ld8_cg(const void* p) {
    u32x2 r;
    asm volatile("global_load_dwordx2 %0, %1, off sc0 sc1" : "=v"(r) : "v"(p) : "memory");
    return r;
}
__device__ inline void st4f_cg(void* p, float v) {
    asm volatile("global_store_dword %0, %1, off sc0 sc1" :: "v"(p), "v"(v) : "memory");
}
__device__ inline void st8_cg(void* p, u32x2 v) {
    asm volatile("global_store_dwordx2 %0, %1, off sc0 sc1" :: "v"(p), "v"(v) : "memory");
}
__device__ inline void st2_cg(void* p, unsigned short v) {
    unsigned w = v;
    asm volatile("global_store_short %0, %1, off sc0 sc1" :: "v"(p), "v"(w) : "memory");
}
__device__ inline void waitvm0(void) {
    asm volatile("s_waitcnt vmcnt(0)" ::: "memory");
    __builtin_amdgcn_sched_barrier(0);
}

// relaxed barrier: no wbl2/inv anywhere (cross-phase data goes through sc0sc1)
__device__ inline void gsync_arrive(int* bar) {
    waitvm0();
    __syncthreads();
    if (threadIdx.x == 0)
        __hip_atomic_fetch_add(bar, 1, __ATOMIC_RELAXED, __HIP_MEMORY_SCOPE_AGENT);
}
__device__ inline void gsync_wait(int* bar, int target) {
    if (threadIdx.x == 0) {
        while (__hip_atomic_load(bar, __ATOMIC_RELAXED, __HIP_MEMORY_SCOPE_AGENT) < target)
            __builtin_amdgcn_s_sleep(2);
    }
    // raw s_barrier: no vmcnt(0) drain -> prefetch loads stay in flight across it
    __builtin_amdgcn_s_barrier();
}
__device__ inline void gsync_c(int* bar, int target) {
    gsync_arrive(bar);
    gsync_wait(bar, target);
}

// ---------------- CSR build (separate kernels: memory-bound, need full TLP) ----------------
__global__ void hist_k(const int* __restrict__ dst, int* __restrict__ counts, int E) {
    int e = blockIdx.x * 256 + threadIdx.x;
    if (e < E) atomicAdd(&counts[dst[e]], 1);
}

__global__ void scan1_k(const int* __restrict__ counts, int* __restrict__ incl,
                        int* __restrict__ bsums, int n) {
    __shared__ int s[256];
    int i = blockIdx.x * 256 + threadIdx.x;
    int v = (i < n) ? counts[i] : 0;
    s[threadIdx.x] = v;
    __syncthreads();
    for (int off = 1; off < 256; off <<= 1) {
        int t = (threadIdx.x >= off) ? s[threadIdx.x - off] : 0;
        __syncthreads();
        s[threadIdx.x] += t;
        __syncthreads();
    }
    if (i < n) incl[i] = s[threadIdx.x];
    if (threadIdx.x == 255) bsums[blockIdx.x] = s[255];
}

__global__ void scan2_k(const int* __restrict__ bsums, int* __restrict__ boffs, int nb) {
    __shared__ int s[128];
    int tid = threadIdx.x;
    int v = (tid < nb) ? bsums[tid] : 0;
    s[tid] = v;
    __syncthreads();
    for (int off = 1; off < 128; off <<= 1) {
        int t = (tid >= off) ? s[tid - off] : 0;
        __syncthreads();
        s[tid] += t;
        __syncthreads();
    }
    if (tid < nb) boffs[tid] = s[tid] - v;
}

__global__ void scan3_k(const int* __restrict__ incl, const int* __restrict__ counts,
                        const int* __restrict__ boffs, int* __restrict__ row_start,
                        int* __restrict__ cursor, int n) {
    int i = blockIdx.x * 256 + threadIdx.x;
    if (i < n) {
        int st = incl[i] - counts[i] + boffs[blockIdx.x];
        row_start[i] = st;
        cursor[i] = st;
    }
}

__global__ void scatter_k(const int* __restrict__ src, const int* __restrict__ dst,
                          const float* __restrict__ w, int* __restrict__ cursor,
                          int2* __restrict__ ep, int E) {
    int e = blockIdx.x * 256 + threadIdx.x;
    if (e < E) {
        int d = dst[e];
        int p = atomicAdd(&cursor[d], 1);
        ep[p] = make_int2(src[e], __float_as_int(w[e]));
    }
}

// mark rows needed by GNN layers 2/3: sel nodes + their in-neighbors.
__global__ void flag_k(const int* __restrict__ idx, const int* __restrict__ row_start,
                       const int* __restrict__ counts, const int2* __restrict__ ep,
                       int* __restrict__ flag) {
    int r4 = blockIdx.x * 4 + (threadIdx.x >> 6);
    int lane = threadIdx.x & 63;
    int id = idx[r4];
    int row = id < 0 ? 0 : id;
    if (lane == 0) flag[row] = 1;
    int beg = row_start[row], cnt = counts[row];
    for (int t = lane; t < cnt; t += 64) flag[ep[beg + t].x] = 1;
}

// ---------------- combined weight conversion (15100 blocks: memory-bound, needs TLP) --------
__global__ void convall_k(const float* __restrict__ gnn_w, const float* __restrict__ post_w,
                          const float* __restrict__ pin_w, const float* __restrict__ blk_w1,
                          const float* __restrict__ blk_w2, const float* __restrict__ pout_w,
                          const float* __restrict__ gene, unsigned short* __restrict__ gnnT,
                          unsigned short* __restrict__ postT, unsigned short* __restrict__ pinT,
                          unsigned short* __restrict__ w1T, unsigned short* __restrict__ w2T,
                          unsigned short* __restrict__ poutT,
                          unsigned short* __restrict__ geneb) {
    int b = blockIdx.x;
    if (b >= 13440) {   // gene: plain fp32 -> bf16 convert, 2048 elems/block
        int t = b - 13440;
        const float4* xp = (const float4*)gene;
        int i = t * 512 + threadIdx.x * 2;    // float4 index
        float4 a = xp[i], c = xp[i + 1];
        *(ushort4*)(geneb + (size_t)i * 4) =
            make_ushort4(f2bf(a.x), f2bf(a.y), f2bf(a.z), f2bf(a.w));
        *(ushort4*)(geneb + (size_t)i * 4 + 4) =
            make_ushort4(f2bf(c.x), f2bf(c.y), f2bf(c.z), f2bf(c.w));
        return;
    }
    const float* W;
    unsigned short* WT;
    int K, N, tile;
    if (b < 192) {
        int l = b >> 6;
        tile = b & 63;
        W = gnn_w + (size_t)l * GDIM * GDIM;
        WT = gnnT + (size_t)l * GDIM * GDIM;
        K = GDIM; N = GDIM;
    } else if (b < 256) {
        tile = b - 192; W = post_w; WT = postT; K = GDIM; N = GDIM;
    } else if (b < 384) {
        tile = b - 256; W = pin_w; WT = pinT; K = GDIM; N = HID;
    } else if (b < 6528) {
        int t = b - 384;
        int l = t >> 10;
        tile = t & 1023;
        W = blk_w1 + (size_t)l * HID * INNER;
        WT = w1T + (size_t)l * INNER * HID;
        K = HID; N = INNER;
    } else if (b < 12672) {
        int t = b - 6528;
        int l = t >> 10;
        tile = t & 1023;
        W = blk_w2 + (size_t)l * INNER * HID;
        WT = w2T + (size_t)l * HID * INNER;
        K = INNER; N = HID;
    } else {
        tile = b - 12672; W = pout_w; WT = poutT; K = HID; N = NCLS * RANK;
    }
    __shared__ float s[32][33];
    int ntx = N >> 5;
    int k0 = (tile / ntx) << 5;
    int n0 = (tile % ntx) << 5;
    int tx = threadIdx.x & 31, ty = threadIdx.x >> 5;
#pragma unroll
    for (int i = 0; i < 4; i++)
        s[ty + 8 * i][tx] = W[(size_t)(k0 + ty + 8 * i) * N + n0 + tx];
    __syncthreads();
#pragma unroll
    for (int i = 0; i < 4; i++)
        WT[(size_t)(n0 + ty + 8 * i) * K + k0 + tx] = f2bf(s[tx][ty + 8 * i]);
}

// ---------------- GNN LayerNorm (D=256), bf16 out; optional row-flag skip ----------------
template <bool FLAGGED>
__global__ void lnb_k(const float* __restrict__ X, const float* __restrict__ sc,
                      const float* __restrict__ bi, unsigned short* __restrict__ Y, int M,
                      const int* __restrict__ flag) {
    int row = blockIdx.x * 4 + (threadIdx.x >> 6);
    int lane = threadIdx.x & 63;
    if (row >= M) return;
    if (FLAGGED && !flag[row]) return;   // wave-uniform skip: stale rows never consumed
    float4 v = ((const float4*)(X + (size_t)row * GDIM))[lane];
    float sum = v.x + v.y + v.z + v.w;
#pragma unroll
    for (int off = 32; off >= 1; off >>= 1) sum += __shfl_xor(sum, off);
    float mu = sum / GDIM;
    float a = v.x - mu, b = v.y - mu, c = v.z - mu, d = v.w - mu;
    float sq = a * a + b * b + c * c + d * d;
#pragma unroll
    for (int off = 32; off >= 1; off >>= 1) sq += __shfl_xor(sq, off);
    float rstd = rsqrtf(sq / GDIM + 1e-5f);
    float4 s4 = ((const float4*)sc)[lane];
    float4 b4 = ((const float4*)bi)[lane];
    *(ushort4*)(Y + (size_t)row * GDIM + lane * 4) =
        make_ushort4(f2bf(a * rstd * s4.x + b4.x), f2bf(b * rstd * s4.y + b4.y),
                     f2bf(c * rstd * s4.z + b4.z), f2bf(d * rstd * s4.w + b4.w));
}

// ---------------- CSR aggregation, 16-deep MLP unroll ----------------
__device__ inline void agg_row(int beg, int cnt, int lane, const int2* __restrict__ ep,
                               const unsigned short* __restrict__ H, float& a0, float& a1,
                               float& a2, float& a3) {
    int t = 0;
    for (; t + 16 <= cnt; t += 16) {
        int2 e[16];
#pragma unroll
        for (int u = 0; u < 16; u++) e[u] = ep[beg + t + u];
        ushort4 v[16];
#pragma unroll
        for (int u = 0; u < 16; u++)
            v[u] = *(const ushort4*)(H + (size_t)e[u].x * GDIM + lane * 4);
#pragma unroll
        for (int u = 0; u < 16; u++) {
            float w = __int_as_float(e[u].y);
            a0 = fmaf(bf2f(v[u].x), w, a0);
            a1 = fmaf(bf2f(v[u].y), w, a1);
            a2 = fmaf(bf2f(v[u].z), w, a2);
            a3 = fmaf(bf2f(v[u].w), w, a3);
        }
    }
    for (; t + 4 <= cnt; t += 4) {
        int2 e[4];
#pragma unroll
        for (int u = 0; u < 4; u++) e[u] = ep[beg + t + u];
        ushort4 v[4];
#pragma unroll
        for (int u = 0; u < 4; u++)
            v[u] = *(const ushort4*)(H + (size_t)e[u].x * GDIM + lane * 4);
#pragma unroll
        for (int u = 0; u < 4; u++) {
            float w = __int_as_float(e[u].y);
            a0 = fmaf(bf2f(v[u].x), w, a0);
            a1 = fmaf(bf2f(v[u].y), w, a1);
            a2 = fmaf(bf2f(v[u].z), w, a2);
            a3 = fmaf(bf2f(v[u].w), w, a3);
        }
    }
    for (; t < cnt; t++) {
        int2 e = ep[beg + t];
        float w = __int_as_float(e.y);
        ushort4 v = *(const ushort4*)(H + (size_t)e.x * GDIM + lane * 4);
        a0 = fmaf(bf2f(v.x), w, a0);
        a1 = fmaf(bf2f(v.y), w, a1);
        a2 = fmaf(bf2f(v.z), w, a2);
        a3 = fmaf(bf2f(v.w), w, a3);
    }
}

template <bool FLAGGED>
__global__ void aggb_k(const int* __restrict__ row_start, const int* __restrict__ counts,
                       const int2* __restrict__ ep, const unsigned short* __restrict__ H,
                       unsigned short* __restrict__ AGG, int n, const int* __restrict__ flag) {
    int row = blockIdx.x * 4 + (threadIdx.x >> 6);
    int lane = threadIdx.x & 63;
    if (row >= n) return;
    if (FLAGGED && !flag[row]) return;   // skip rows whose x2 is never consumed
    float a0 = 0.f, a1 = 0.f, a2 = 0.f, a3 = 0.f;
    agg_row(row_start[row], counts[row], lane, ep, H, a0, a1, a2, a3);
    *(ushort4*)(AGG + (size_t)row * GDIM + lane * 4) =
        make_ushort4(f2bf(a0), f2bf(a1), f2bf(a2), f2bf(a3));
}

// ---------------- bf16 MFMA GEMM (full-K, fp32 out, fused epilogue) — GNN L1/L2 & logits ----------------
template <int ACT, bool RES, bool BIAS>
__global__ __launch_bounds__(256) void mgemm_k(const unsigned short* __restrict__ A,
                                               const unsigned short* __restrict__ BT,
                                               const float* __restrict__ bias,
                                               const float* __restrict__ R,
                                               float* __restrict__ C, int M, int N, int K) {
    __shared__ unsigned short As[128 * 32];
    __shared__ unsigned short Bs[128 * 32];
    int m0 = blockIdx.y * 128, n0 = blockIdx.x * 128;
    int tid = threadIdx.x;
    int wave = tid >> 6, lane = tid & 63;
    int wm = (wave >> 1) * 64, wn = (wave & 1) * 64;
    int lrow = lane & 15, lq = lane >> 4;

    f32x4 acc[4][4];
    const f32x4 zz = {0.f, 0.f, 0.f, 0.f};
#pragma unroll
    for (int i = 0; i < 4; i++)
#pragma unroll
        for (int j = 0; j < 4; j++) acc[i][j] = zz;

    int r0 = tid >> 2;
    int q = tid & 3;

    for (int k0 = 0; k0 < K; k0 += 32) {
#pragma unroll
        for (int p = 0; p < 2; p++) {
            int row = r0 + p * 64;
            int gm = m0 + row;
            uint4 va = make_uint4(0, 0, 0, 0);
            if (gm < M) va = *(const uint4*)(A + (size_t)gm * K + k0 + q * 8);
            *(uint4*)&As[row * 32 + q * 8] = va;
            int gn = n0 + row;
            uint4 vb = make_uint4(0, 0, 0, 0);
            if (gn < N) vb = *(const uint4*)(BT + (size_t)gn * K + k0 + q * 8);
            *(uint4*)&Bs[row * 32 + q * 8] = vb;
        }
        __syncthreads();
        bf16x8 af[4], bf[4];
#pragma unroll
        for (int i = 0; i < 4; i++)
            af[i] = *(const bf16x8*)&As[(wm + i * 16 + lrow) * 32 + lq * 8];
#pragma unroll
        for (int j = 0; j < 4; j++)
            bf[j] = *(const bf16x8*)&Bs[(wn + j * 16 + lrow) * 32 + lq * 8];
#pragma unroll
        for (int i = 0; i < 4; i++)
#pragma unroll
            for (int j = 0; j < 4; j++)
                acc[i][j] =
                    __builtin_amdgcn_mfma_f32_16x16x32_bf16(af[i], bf[j], acc[i][j], 0, 0, 0);
        __syncthreads();
    }

#pragma unroll
    for (int i = 0; i < 4; i++) {
#pragma unroll
        for (int j = 0; j < 4; j++) {
            int gn = n0 + wn + j * 16 + lrow;
            if (gn >= N) continue;
            float bv = BIAS ? bias[gn] : 0.f;
#pragma unroll
            for (int r = 0; r < 4; r++) {
                int gm = m0 + wm + i * 16 + lq * 4 + r;
                if (gm >= M) continue;
                float v = acc[i][j][r] + bv;
                if (ACT == 1) v = fmaxf(v, 0.f);
                if (RES) v += R[(size_t)gm * N + gn];
                C[(size_t)gm * N + gn] = v;
            }
        }
    }
}

// ================= fused persistent head (v7: row-groups + prefetch + aggsel/L3/post prologue) =
// Group g (blocks g*32..g*32+31) owns batch rows [32g,32g+32); per-group barriers
// (proven 178 -> 112); arrive->prefetch->wait split (proven 122 -> 88). The three
// 256-row tail ops (aggsel gather, GNN-L3 GEMM, post GEMM) are group-local -> folded
// in as 3 prologue phases (verified correct in round 10).

#define HGRID 256
#define LDPA 520   // ushort row stride for K<=512 tiles: 1040B -> bank-optimal b128 reads
#define GBLK 32    // blocks per group

// issue ROWSxKC bf16 tile loads (all outstanding), NL = ROWS*KC/2048 regs/thread
template <int ROWS, int KC, bool CG>
__device__ inline void stage_issue(const unsigned short* src, int ld, u32x4* regs) {
    constexpr int NL = ROWS * KC / 8 / 256;
    int tid = threadIdx.x;
#pragma unroll
    for (int it = 0; it < NL; it++) {
        int unit = it * 256 + tid;
        int row = unit / (KC / 8);
        int ucol = unit % (KC / 8);
        const unsigned short* p = src + (size_t)row * ld + ucol * 8;
        if (CG) regs[it] = ld16_cg(p);
        else regs[it] = *(const u32x4*)p;
    }
}
template <int ROWS, int KC>
__device__ inline void stage_write(unsigned short* dst, const u32x4* regs) {
    constexpr int NL = ROWS * KC / 8 / 256;
    int tid = threadIdx.x;
#pragma unroll
    for (int it = 0; it < NL; it++) {
        int unit = it * 256 + tid;
        int row = unit / (KC / 8);
        int ucol = unit % (KC / 8);
        *(u32x4*)&dst[row * LDPA + ucol * 8] = regs[it];
    }
}

// uninterrupted MFMA stream over the fully-staged tile (no inner barriers)
template <int KC>
__device__ inline void mma_all(const unsigned short* As, const unsigned short* Bs, f32x4 acc[2]) {
    int tid = threadIdx.x, wave = tid >> 6, lane = tid & 63;
    int wm = (wave >> 1) * 16, wn = (wave & 1) * 32;
    int lrow = lane & 15, lq = lane >> 4;
#pragma unroll
    for (int kk = 0; kk < KC / 32; kk++) {
        bf16x8 af = *(const bf16x8*)&As[(wm + lrow) * LDPA + kk * 32 + lq * 8];
#pragma unroll
        for (int j = 0; j < 2; j++) {
            bf16x8 bfr = *(const bf16x8*)&Bs[(wn + j * 16 + lrow) * LDPA + kk * 32 + lq * 8];
            acc[j] = __builtin_amdgcn_mfma_f32_16x16x32_bf16(af, bfr, acc[j], 0, 0, 0);
        }
    }
}

__global__ __launch_bounds__(256) void head_k(
    const int* __restrict__ node_indices, const int* __restrict__ row_start,
    const int* __restrict__ counts, const int2* __restrict__ ep,
    const unsigned short* __restrict__ lnbf, const unsigned short* __restrict__ gnnT3,
    const float* __restrict__ gnnb3, const float* __restrict__ xb,
    const unsigned short* __restrict__ postT, const float* __restrict__ post_b,
    const float* __restrict__ oov_emb, unsigned short* __restrict__ aggselb,
    unsigned short* __restrict__ pertinbf, unsigned short* __restrict__ pertbf,
    const unsigned short* __restrict__ pinT, const float* __restrict__ pin_b,
    const float* __restrict__ blk_ln_s, const float* __restrict__ blk_ln_b,
    const unsigned short* __restrict__ w1T, const float* __restrict__ blk_b1,
    const unsigned short* __restrict__ w2T, const float* __restrict__ blk_b2,
    const unsigned short* __restrict__ poutT, const float* __restrict__ pout_b,
    float* __restrict__ hbuf, unsigned short* __restrict__ z1bf,
    unsigned short* __restrict__ projb, int* __restrict__ bar) {
    __shared__ unsigned short As[32 * LDPA];   // 33.3 KB
    __shared__ unsigned short Bs[64 * LDPA];   // 66.6 KB
    int b = blockIdx.x;
    int g = b >> 5;          // row-group 0..7: batch rows [g*32, g*32+32)
    int t = b & 31;          // rank within group; b%8 == t%8 -> XCD locality by n-slice
    int* gbar = bar + g * 32;   // per-group counter, 128 B apart
    int m0 = g * 32;
    int tid = threadIdx.x;
    int wave = tid >> 6, lane = tid & 63;
    int wm = (wave >> 1) * 16, wn = (wave & 1) * 32;
    int lrow = lane & 15, lq = lane >> 4;
    int ph = 0;
    f32x4 acc[2];
    const f32x4 zz = {0.f, 0.f, 0.f, 0.f};
    u32x4 pf[16];   // weight prefetch registers, live across the barrier (1 block/CU)

    // ---- P-3: aggsel — block t gathers for batch row m0+t (4-wave edge split + LDS reduce)
    {
        int bb = m0 + t;
        int id = node_indices[bb];
        int row = id < 0 ? 0 : id;
        int beg = row_start[row], cnt = counts[row];
        float a0 = 0.f, a1 = 0.f, a2 = 0.f, a3 = 0.f;
        for (int e2 = wave; e2 < cnt; e2 += 4) {
            int2 ed = ep[beg + e2];
            float w = __int_as_float(ed.y);
            ushort4 v = *(const ushort4*)(lnbf + (size_t)ed.x * GDIM + lane * 4);
            a0 = fmaf(bf2f(v.x), w, a0);
            a1 = fmaf(bf2f(v.y), w, a1);
            a2 = fmaf(bf2f(v.z), w, a2);
            a3 = fmaf(bf2f(v.w), w, a3);
        }
        float* red = (float*)As;
        red[wave * 256 + lane * 4 + 0] = a0;
        red[wave * 256 + lane * 4 + 1] = a1;
        red[wave * 256 + lane * 4 + 2] = a2;
        red[wave * 256 + lane * 4 + 3] = a3;
        __syncthreads();
        if (wave == 0) {
            float s0 = red[lane * 4] + red[256 + lane * 4] + red[512 + lane * 4] +
                       red[768 + lane * 4];
            float s1 = red[lane * 4 + 1] + red[256 + lane * 4 + 1] + red[512 + lane * 4 + 1] +
                       red[768 + lane * 4 + 1];
            float s2 = red[lane * 4 + 2] + red[256 + lane * 4 + 2] + red[512 + lane * 4 + 2] +
                       red[768 + lane * 4 + 2];
            float s3 = red[lane * 4 + 3] + red[256 + lane * 4 + 3] + red[512 + lane * 4 + 3] +
                       red[768 + lane * 4 + 3];
            u32x2 pk;
            pk[0] = pk2(s0, s1);
            pk[1] = pk2(s2, s3);
            st8_cg(aggselb + (size_t)bb * GDIM + lane * 4, pk);
        }
    }
    gsync_c(gbar, ++ph * GBLK);

    // ---- P-2: pertin = relu(aggsel @ W3 + b3) + xb[idx]  (t<4: 32x64 col slices, K=256)
    if (t < 4) {
        int n0 = t * 64;
        u32x4 wreg[8], areg[4];
        stage_issue<64, 256, false>(gnnT3 + (size_t)n0 * GDIM, GDIM, wreg);
        stage_issue<32, 256, true>(aggselb + (size_t)m0 * GDIM, GDIM, areg);
        waitvm0();
        stage_write<64, 256>(Bs, wreg);
        stage_write<32, 256>(As, areg);
        __syncthreads();
        acc[0] = zz; acc[1] = zz;
        mma_all<256>(As, Bs, acc);
#pragma unroll
        for (int j = 0; j < 2; j++) {
            int gn = n0 + wn + j * 16 + lrow;
            float bv = gnnb3[gn];
#pragma unroll
            for (int r = 0; r < 4; r++) {
                int gmb = m0 + wm + lq * 4 + r;
                float v = fmaxf(acc[j][r] + bv, 0.f);
                int id = node_indices[gmb];
                int safe = id < 0 ? 0 : id;
                v += xb[(size_t)safe * GDIM + gn];
                st2_cg(pertinbf + (size_t)gmb * GDIM + gn, f2bf(v));
            }
        }
    }
    gsync_c(gbar, ++ph * GBLK);

    // ---- P-1: pert = pertin @ postW + post_b; OOV rows replaced by oov_emb
    if (t < 4) {
        int n0 = t * 64;
        u32x4 wreg[8], areg[4];
        stage_issue<64, 256, false>(postT + (size_t)n0 * GDIM, GDIM, wreg);
        stage_issue<32, 256, true>(pertinbf + (size_t)m0 * GDIM, GDIM, areg);
        waitvm0();
        stage_write<64, 256>(Bs, wreg);
        stage_write<32, 256>(As, areg);
        __syncthreads();
        acc[0] = zz; acc[1] = zz;
        mma_all<256>(As, Bs, acc);
#pragma unroll
        for (int j = 0; j < 2; j++) {
            int gn = n0 + wn + j * 16 + lrow;
            float bv = post_b[gn];
#pragma unroll
            for (int r = 0; r < 4; r++) {
                int gmb = m0 + wm + lq * 4 + r;
                float v = acc[j][r] + bv;
                if (node_indices[gmb] < 0) v = oov_emb[gn];
                st2_cg(pertbf + (size_t)gmb * GDIM + gn, f2bf(v));
            }
        }
    }
    gsync_c(gbar, ++ph * GBLK);

    // ---- P0: h[g-rows] = pert @ pinT + pin_b  (8 active blocks/group, full K=256)
    if (t < 8) {
        int n0 = t * 64;
        u32x4 wreg[8], areg[4];
        stage_issue<64, 256, false>(pinT + (size_t)n0 * GDIM, GDIM, wreg);
        stage_issue<32, 256, true>(pertbf + (size_t)m0 * GDIM, GDIM, areg);
        waitvm0();
        stage_write<64, 256>(Bs, wreg);
        stage_write<32, 256>(As, areg);
        __syncthreads();
        acc[0] = zz; acc[1] = zz;
        mma_all<256>(As, Bs, acc);
#pragma unroll
        for (int j = 0; j < 2; j++) {
            int gn = n0 + wn + j * 16 + lrow;
            float bv = pin_b[gn];
#pragma unroll
            for (int r = 0; r < 4; r++) {
                int gm = m0 + wm + lq * 4 + r;
                st4f_cg(hbuf + (size_t)gm * HID + gn, acc[j][r] + bv);
            }
        }
    }
    // arrive -> issue layer-0 w1 prefetch -> poll: load latency hides under the poll
    gsync_arrive(gbar);
    stage_issue<64, 512, false>(w1T + (size_t)t * 64 * HID, HID, pf);
    gsync_wait(gbar, ++ph * GBLK);

    for (int i = 0; i < 6; i++) {
        {   // A: z1[g-rows] = gelu(LN_i(h) @ w1 + b1); 32 blocks x 64-col slices, K=512
            int n0 = t * 64;
            u32x4 hreg[16];
#pragma unroll
            for (int rr = 0; rr < 8; rr++) {
                const float* p = hbuf + (size_t)(m0 + wave * 8 + rr) * HID + lane * 8;
                hreg[2 * rr] = ld16_cg(p);
                hreg[2 * rr + 1] = ld16_cg(p + 4);
            }
            stage_write<64, 512>(Bs, pf);   // compiler inserts counted wait for pf here
            waitvm0();
            // inline LayerNorm (redundant across the 32 n-slices, cheap) -> bf16 As
            const float* ls = blk_ln_s + (size_t)i * HID;
            const float* lb = blk_ln_b + (size_t)i * HID;
            float4 s0 = ((const float4*)ls)[lane * 2], s1 = ((const float4*)ls)[lane * 2 + 1];
            float4 t0 = ((const float4*)lb)[lane * 2], t1 = ((const float4*)lb)[lane * 2 + 1];
#pragma unroll
            for (int rr = 0; rr < 8; rr++) {
                float f0 = __uint_as_float(hreg[2 * rr][0]);
                float f1 = __uint_as_float(hreg[2 * rr][1]);
                float f2 = __uint_as_float(hreg[2 * rr][2]);
                float f3 = __uint_as_float(hreg[2 * rr][3]);
                float f4 = __uint_as_float(hreg[2 * rr + 1][0]);
                float f5 = __uint_as_float(hreg[2 * rr + 1][1]);
                float f6 = __uint_as_float(hreg[2 * rr + 1][2]);
                float f7 = __uint_as_float(hreg[2 * rr + 1][3]);
                float sum = f0 + f1 + f2 + f3 + f4 + f5 + f6 + f7;
#pragma unroll
                for (int off = 32; off >= 1; off >>= 1) sum += __shfl_xor(sum, off);
                float mu = sum * (1.f / HID);
                float d0 = f0 - mu, d1 = f1 - mu, d2 = f2 - mu, d3 = f3 - mu;
                float d4 = f4 - mu, d5 = f5 - mu, d6 = f6 - mu, d7 = f7 - mu;
                float sq = d0 * d0 + d1 * d1 + d2 * d2 + d3 * d3 + d4 * d4 + d5 * d5 +
                           d6 * d6 + d7 * d7;
#pragma unroll
                for (int off = 32; off >= 1; off >>= 1) sq += __shfl_xor(sq, off);
                float rstd = rsqrtf(sq * (1.f / HID) + 1e-5f);
                u32x4 pk;
                pk[0] = pk2(d0 * rstd * s0.x + t0.x, d1 * rstd * s0.y + t0.y);
                pk[1] = pk2(d2 * rstd * s0.z + t0.z, d3 * rstd * s0.w + t0.w);
                pk[2] = pk2(d4 * rstd * s1.x + t1.x, d5 * rstd * s1.y + t1.y);
                pk[3] = pk2(d6 * rstd * s1.z + t1.z, d7 * rstd * s1.w + t1.w);
                *(u32x4*)&As[(wave * 8 + rr) * LDPA + lane * 8] = pk;
            }
            __syncthreads();
            acc[0] = zz; acc[1] = zz;
            mma_all<512>(As, Bs, acc);
#pragma unroll
            for (int j = 0; j < 2; j++) {
                int gn = n0 + wn + j * 16 + lrow;
                float bv = blk_b1[(size_t)i * INNER + gn];
#pragma unroll
                for (int r = 0; r < 4; r++) {
                    int gm = m0 + wm + lq * 4 + r;
                    float v = acc[j][r] + bv;
                    v = 0.5f * v * (1.f + erff(v * 0.70710678118654752f));
                    st2_cg(z1bf + (size_t)gm * INNER + gn, f2bf(v));
                }
            }
        }
        // arrive -> prefetch my B-phase w2 slice -> poll
        gsync_arrive(gbar);
        stage_issue<64, 512, false>(
            w2T + (size_t)i * HID * INNER + (size_t)(t & 7) * 64 * INNER + (t >> 3) * 512,
            INNER, pf);
        gsync_wait(gbar, ++ph * GBLK);
        {   // B: h[g-rows] += z1 @ w2 K-chunk (+b2 once via s==0); 8n x 4s per group
            int s = t >> 3, n0 = (t & 7) * 64, kbeg = s * 512;
            u32x4 areg[8];
            stage_issue<32, 512, true>(z1bf + (size_t)m0 * INNER + kbeg, INNER, areg);
            stage_write<64, 512>(Bs, pf);
            waitvm0();
            stage_write<32, 512>(As, areg);
            __syncthreads();
            acc[0] = zz; acc[1] = zz;
            mma_all<512>(As, Bs, acc);
#pragma unroll
            for (int j = 0; j < 2; j++) {
                int gn = n0 + wn + j * 16 + lrow;
                float bv = (s == 0) ? blk_b2[(size_t)i * HID + gn] : 0.f;
#pragma unroll
                for (int r = 0; r < 4; r++) {
                    int gm = m0 + wm + lq * 4 + r;
                    __hip_atomic_fetch_add(hbuf + (size_t)gm * HID + gn, acc[j][r] + bv,
                                           __ATOMIC_RELAXED, __HIP_MEMORY_SCOPE_AGENT);
                }
            }
        }
        // arrive -> prefetch next A-phase w1 (or pout slice after last layer) -> poll
        gsync_arrive(gbar);
        if (i < 5)
            stage_issue<64, 512, false>(
                w1T + (size_t)(i + 1) * INNER * HID + (size_t)t * 64 * HID, HID, pf);
        else if (t < 24)
            stage_issue<64, 512, false>(poutT + (size_t)t * 64 * HID, HID, pf);
        gsync_wait(gbar, ++ph * GBLK);
    }

    // ---- pout: projb[g-rows] = h @ poutT + pout_b  (24 active blocks/group, K=512)
    if (t < 24) {
        int n0 = t * 64;
        u32x4 areg[16];
#pragma unroll
        for (int it = 0; it < 16; it++) {
            int unit = it * 256 + tid;
            int row = unit >> 7, ucol = unit & 127;   // 128 units of 4 f32 per row
            areg[it] = ld16_cg(hbuf + (size_t)(m0 + row) * HID + ucol * 4);
        }
        stage_write<64, 512>(Bs, pf);
        waitvm0();
#pragma unroll
        for (int it = 0; it < 16; it++) {
            int unit = it * 256 + tid;
            int row = unit >> 7, ucol = unit & 127;
            float a = __uint_as_float(areg[it][0]), c = __uint_as_float(areg[it][1]);
            float d = __uint_as_float(areg[it][2]), e = __uint_as_float(areg[it][3]);
            uint2 w2v;
            w2v.x = pk2(a, c);
            w2v.y = pk2(d, e);
            *(uint2*)&As[row * LDPA + ucol * 4] = w2v;
        }
        __syncthreads();
        acc[0] = zz; acc[1] = zz;
        mma_all<512>(As, Bs, acc);
#pragma unroll
        for (int j = 0; j < 2; j++) {
            int gn = n0 + wn + j * 16 + lrow;
            float bv = pout_b[gn];
#pragma unroll
            for (int r = 0; r < 4; r++) {
                int gm = m0 + wm + lq * 4 + r;
                projb[(size_t)gm * (NCLS * RANK) + gn] = f2bf(acc[j][r] + bv);
            }
        }
    }
}

// ---------------- launch ----------------
extern "C" void kernel_launch(void* const* d_in, const int* in_sizes, int n_in,
                              void* d_out, int out_size, void* d_ws, size_t ws_size,
                              hipStream_t stream) {
    const int* node_indices = (const int*)d_in[0];
    const int* edge_src = (const int*)d_in[1];
    const int* edge_dst = edge_src + NEDGES;
    const float* edge_w = (const float*)d_in[2];
    const float* partial_emb = (const float*)d_in[3];
    const float* oov_emb = (const float*)d_in[4];
    const float* gnn_ln_s = (const float*)d_in[5];
    const float* gnn_ln_b = (const float*)d_in[6];
    const float* gnn_w = (const float*)d_in[7];
    const float* gnn_b = (const float*)d_in[8];
    const float* post_w = (const float*)d_in[9];
    const float* post_b = (const float*)d_in[10];
    const float* pin_w = (const float*)d_in[11];
    const float* pin_b = (const float*)d_in[12];
    const float* blk_ln_s = (const float*)d_in[13];
    const float* blk_ln_b = (const float*)d_in[14];
    const float* blk_w1 = (const float*)d_in[15];
    const float* blk_b1 = (const float*)d_in[16];
    const float* blk_w2 = (const float*)d_in[17];
    const float* blk_b2 = (const float*)d_in[18];
    const float* pout_w = (const float*)d_in[19];
    const float* pout_b = (const float*)d_in[20];
    const float* gene = (const float*)d_in[21];
    float* out = (float*)d_out;

    char* p = (char*)d_ws;
    auto alloc = [&](size_t bytes) {
        char* r = p;
        p += (bytes + 255) & ~(size_t)255;
        return r;
    };
    int* counts = (int*)alloc(NNODES * 4);
    int* incl = (int*)alloc(NNODES * 4);
    int* bsums = (int*)alloc(128 * 4);
    int* boffs = (int*)alloc(128 * 4);
    int* row_start = (int*)alloc(NNODES * 4);
    int* cursor = (int*)alloc(NNODES * 4);
    int* flag = (int*)alloc(NNODES * 4);
    int2* epack = (int2*)alloc((size_t)NEDGES * 8);
    // GNN phase scratch = ln_bf + aggbf (bf16)
    float* part = (float*)alloc((size_t)NNODES * GDIM * 4);
    unsigned short* ln_bf = (unsigned short*)part;
    unsigned short* aggbf = (unsigned short*)((char*)part + (size_t)NNODES * GDIM * 2);
    float* xa = (float*)alloc((size_t)NNODES * GDIM * 4);
    float* xb = (float*)alloc((size_t)NNODES * GDIM * 4);
    float* hbuf = (float*)alloc((size_t)BSZ * HID * 4);
    unsigned short* aggselb = (unsigned short*)alloc((size_t)BSZ * GDIM * 2);
    unsigned short* pertinbf = (unsigned short*)alloc((size_t)BSZ * GDIM * 2);
    unsigned short* pertbf = (unsigned short*)alloc((size_t)BSZ * GDIM * 2);
    unsigned short* z1bf = (unsigned short*)alloc((size_t)BSZ * INNER * 2);
    unsigned short* projb = (unsigned short*)alloc((size_t)BSZ * NCLS * RANK * 2);
    unsigned short* gnnT = (unsigned short*)alloc((size_t)3 * GDIM * GDIM * 2);
    unsigned short* postT = (unsigned short*)alloc((size_t)GDIM * GDIM * 2);
    unsigned short* pinT = (unsigned short*)alloc((size_t)HID * GDIM * 2);
    unsigned short* w1T = (unsigned short*)alloc((size_t)6 * INNER * HID * 2);
    unsigned short* w2T = (unsigned short*)alloc((size_t)6 * HID * INNER * 2);
    unsigned short* poutT = (unsigned short*)alloc((size_t)NCLS * RANK * HID * 2);
    unsigned short* geneb = (unsigned short*)alloc((size_t)NGENES * RANK * 2);
    int* bar = (int*)alloc(1024);   // 8 head group counters, 128 B apart

    const int EB = (NEDGES + 255) / 256;
    const int NB = (NNODES + 255) / 256;

    // all weight conversions in one wide dispatch (memory-bound: needs TLP)
    convall_k<<<15100, 256, 0, stream>>>(gnn_w, post_w, pin_w, blk_w1, blk_w2, pout_w, gene,
                                         gnnT, postT, pinT, w1T, w2T, poutT, geneb);

    // CSR build
    (void)hipMemsetAsync(counts, 0, NNODES * 4, stream);
    (void)hipMemsetAsync(flag, 0, NNODES * 4, stream);
    (void)hipMemsetAsync(bar, 0, 1024, stream);
    hist_k<<<EB, 256, 0, stream>>>(edge_dst, counts, NEDGES);
    scan1_k<<<NB, 256, 0, stream>>>(counts, incl, bsums, NNODES);
    scan2_k<<<1, 128, 0, stream>>>(bsums, boffs, NB);
    scan3_k<<<NB, 256, 0, stream>>>(incl, counts, boffs, row_start, cursor, NNODES);
    scatter_k<<<EB, 256, 0, stream>>>(edge_src, edge_dst, edge_w, cursor, epack, NEDGES);
    // rows needed by layers 2/3: selected nodes + their in-neighbors
    flag_k<<<BSZ / 4, 256, 0, stream>>>(node_indices, row_start, counts, epack, flag);

    // GNN layer 1 (full) and layer 2 (flagged destination rows only)
    const float* x_in = partial_emb;
    float* bufs[2] = {xa, xb};
    for (int i = 0; i < 2; i++) {
        lnb_k<false><<<(NNODES + 3) / 4, 256, 0, stream>>>(
            x_in, gnn_ln_s + i * GDIM, gnn_ln_b + i * GDIM, ln_bf, NNODES, nullptr);
        if (i == 0)
            aggb_k<false><<<(NNODES + 3) / 4, 256, 0, stream>>>(row_start, counts, epack, ln_bf,
                                                                aggbf, NNODES, nullptr);
        else
            aggb_k<true><<<(NNODES + 3) / 4, 256, 0, stream>>>(row_start, counts, epack, ln_bf,
                                                               aggbf, NNODES, flag);
        float* x_out = bufs[i];
        mgemm_k<1, true, true><<<dim3(GDIM / 128, (NNODES + 127) / 128), 256, 0, stream>>>(
            aggbf, gnnT + (size_t)i * GDIM * GDIM, gnn_b + i * GDIM, x_in, x_out, NNODES, GDIM,
            GDIM);
        x_in = x_out;
    }
    // layer 3 LN: only flagged rows (sources of selected rows' edges)
    lnb_k<true><<<(NNODES + 3) / 4, 256, 0, stream>>>(xb, gnn_ln_s + 2 * GDIM,
                                                      gnn_ln_b + 2 * GDIM, ln_bf, NNODES, flag);

    // fused head: aggsel + L3 + post + pin + 6 blocks + pout (16 group barriers)
    head_k<<<HGRID, 256, 0, stream>>>(node_indices, row_start, counts, epack, ln_bf,
                                      gnnT + (size_t)2 * GDIM * GDIM, gnn_b + 2 * GDIM, xb,
                                      postT, post_b, oov_emb, aggselb, pertinbf, pertbf, pinT,
                                      pin_b, blk_ln_s, blk_ln_b, w1T, blk_b1, w2T, blk_b2,
                                      poutT, pout_b, hbuf, z1bf, projb, bar);

    // logits
    mgemm_k<0, false, false><<<dim3((NGENES + 127) / 128, (BSZ * NCLS) / 128), 256, 0, stream>>>(
        projb, geneb, nullptr, nullptr, out, BSZ * NCLS, NGENES, RANK);
}